// Round 10
// baseline (139.596 us; speedup 1.0000x reference)
//
#include <hip/hip_runtime.h>

typedef unsigned short ushort_t;
typedef short s16x8 __attribute__((ext_vector_type(8)));   // bf16 frag vector
typedef float f32x4 __attribute__((ext_vector_type(4)));

#define DEVINL __device__ __forceinline__

DEVINL ushort_t f2b(float f) {           // fp32 -> bf16 RNE
  union { float f; unsigned int u; } v; v.f = f;
  unsigned int r = (v.u + 0x7fffu + ((v.u >> 16) & 1u)) >> 16;
  return (ushort_t)r;
}

DEVINL ushort_t f2b_hw(float f) {        // fp32 -> bf16 via HW v_cvt (RNE)
  union { __bf16 h; ushort_t u; } cv;
  cv.h = (__bf16)f;
  return cv.u;
}

// ---------- prep: fused {Wqkv transpose, Wout transpose, fold} ----------
__global__ __launch_bounds__(256) void prep_kernel(
    const float* __restrict__ Wqkv, const float* __restrict__ bq,
    const float* __restrict__ Wod, const float* __restrict__ bod,
    const float* __restrict__ Wout,
    ushort_t* __restrict__ WqkvT, ushort_t* __restrict__ WoT,
    float* __restrict__ Wcomb, float* __restrict__ bcomb)
{
  __shared__ ushort_t tile[64 * 72];
  const int b = blockIdx.x;
  const int tid = threadIdx.x;

  if (b < 256) {
    const float* in;
    ushort_t* out;
    int N, bx, by;
    if (b < 192) { in = Wqkv; out = WqkvT; N = 1536; bx = b % 24; by = b / 24; }
    else         { in = Wout; out = WoT;   N = 512;  bx = (b - 192) % 8; by = (b - 192) / 8; }
    const int K = 512;
    const int n0 = bx * 64, k0 = by * 64;
    const int cr = tid >> 4;
    const int cc = (tid & 15) * 4;
#pragma unroll
    for (int p = 0; p < 4; p++) {
      int k = k0 + p * 16 + cr;
      float4 v = *(const float4*)(in + k * N + n0 + cc);
      ushort4 o; o.x = f2b(v.x); o.y = f2b(v.y); o.z = f2b(v.z); o.w = f2b(v.w);
      *(ushort4*)(tile + (p * 16 + cr) * 72 + cc) = o;
    }
    __syncthreads();
#pragma unroll
    for (int p = 0; p < 4; p++) {
      int n = n0 + p * 16 + cr;
      ushort4 v;
      v.x = tile[(cc + 0) * 72 + p * 16 + cr];
      v.y = tile[(cc + 1) * 72 + p * 16 + cr];
      v.z = tile[(cc + 2) * 72 + p * 16 + cr];
      v.w = tile[(cc + 3) * 72 + p * 16 + cr];
      *(ushort4*)(out + n * K + k0 + cc) = v;
    }
    return;
  }

  // fold: one wave per c-row
  const int w = tid >> 6, lane = tid & 63;
  const int c = (b - 256) * 4 + w;
  if (c > 512) return;
  float a[8];
  const float* src = (c < 512) ? (Wqkv + c * 1536 + lane * 8) : (bq + lane * 8);
  float4 a0 = *(const float4*)(src);
  float4 a1 = *(const float4*)(src + 4);
  a[0]=a0.x; a[1]=a0.y; a[2]=a0.z; a[3]=a0.w;
  a[4]=a1.x; a[5]=a1.y; a[6]=a1.z; a[7]=a1.w;

  float s[16];
#pragma unroll
  for (int j = 0; j < 16; j++) s[j] = 0.f;
#pragma unroll
  for (int i = 0; i < 8; i++) {
    const float* wp = Wod + (lane * 8 + i) * 16;
#pragma unroll
    for (int j = 0; j < 16; j++) s[j] += a[i] * wp[j];
  }
#pragma unroll
  for (int mask = 1; mask < 64; mask <<= 1)
#pragma unroll
    for (int j = 0; j < 16; j++) s[j] += __shfl_xor(s[j], mask);

  if (lane < 16) {
    if (c < 512) Wcomb[c * 16 + lane] = s[lane];
    else         bcomb[lane] = s[lane] + bod[lane];
  }
}

// ---------------- od (fp32) + x->bf16 conversion fused ----------------
__global__ __launch_bounds__(256) void od_kernel(
    const float* __restrict__ x, const float* __restrict__ Wcomb,
    const float* __restrict__ bcomb, const int* __restrict__ lenp,
    float* __restrict__ params, ushort_t* __restrict__ xb)
{
  const int w = threadIdx.x >> 6, lane = threadIdx.x & 63;
  const int m = blockIdx.x * 4 + w;   // 0..2047
  int li = lenp[0];
  float len = (li > 0 && li < 1048576) ? (float)li : 1024.0f;

  const float* qp = x + m * 512 + lane * 8;
  float q[8];
  float4 qa = *(const float4*)(qp);
  float4 qb = *(const float4*)(qp + 4);
  q[0]=qa.x; q[1]=qa.y; q[2]=qa.z; q[3]=qa.w;
  q[4]=qb.x; q[5]=qb.y; q[6]=qb.z; q[7]=qb.w;

  s16x8 ov;
#pragma unroll
  for (int i = 0; i < 8; i++) ov[i] = (short)f2b(q[i]);
  *(s16x8*)(xb + m * 512 + lane * 8) = ov;

  float s[16];
#pragma unroll
  for (int j = 0; j < 16; j++) s[j] = 0.f;
#pragma unroll
  for (int i = 0; i < 8; i++) {
    const float* wp = Wcomb + (lane * 8 + i) * 16;
#pragma unroll
    for (int j = 0; j < 16; j++) s[j] += q[i] * wp[j];
  }
#pragma unroll
  for (int mask = 1; mask < 64; mask <<= 1)
#pragma unroll
    for (int j = 0; j < 16; j++) s[j] += __shfl_xor(s[j], mask);

  if (lane < 8) {
    int h = lane;
    int bb = m >> 10, t = m & 1023;
    float odo = s[h] + bcomb[h];
    float odd = s[8 + h] + bcomb[8 + h];
    float offset = tanhf(odo) * len;
    float dur = len / (1.f + expf(-odd));
    float anchor = (float)t + offset;
    float start = anchor - dur, end = anchor + dur;
    float bl = floorf(start), br = ceilf(end);
    float al = floorf(anchor);
    float da = anchor - al;
    float* pp = params + ((bb * 8 + h) * 1024 + t) * 6;
    pp[0] = bl; pp[1] = br; pp[2] = al;
    pp[3] = bl - start; pp[4] = end - br; pp[5] = da;
  }
}

// ------- qkv GEMM: 64x128 tiles, grid (12,32); Q pre-scaled 0.125; VT direct -------
__global__ __launch_bounds__(256) void qkv_gemm_kernel(
    const ushort_t* __restrict__ xb, const ushort_t* __restrict__ WT,
    const float* __restrict__ bqkv,
    ushort_t* __restrict__ Qh, ushort_t* __restrict__ Kh, ushort_t* __restrict__ VT)
{
  __shared__ ushort_t As[64 * 32];
  __shared__ ushort_t Bs[128 * 32];
  const int tid = threadIdx.x;
  const int lane = tid & 63, w = tid >> 6;
  const int wr = w >> 1, wc = w & 1;          // wave tile 32x64
  const int quad = lane >> 4, l16 = lane & 15;
  const int m0 = blockIdx.y * 64, n0 = blockIdx.x * 128;

  f32x4 acc[2][4];
#pragma unroll
  for (int i = 0; i < 2; i++)
#pragma unroll
    for (int j = 0; j < 4; j++) acc[i][j] = f32x4{0.f, 0.f, 0.f, 0.f};

  const int idx = tid * 8;
  const int ra = idx >> 5, ca = idx & 31;
  const int rb1 = (idx + 2048) >> 5, cb1 = (idx + 2048) & 31;

  for (int k0 = 0; k0 < 512; k0 += 32) {
    s16x8 va  = *(const s16x8*)(xb + (m0 + ra) * 512 + k0 + ca);
    s16x8 vb0 = *(const s16x8*)(WT + (n0 + ra) * 512 + k0 + ca);
    s16x8 vb1 = *(const s16x8*)(WT + (n0 + rb1) * 512 + k0 + cb1);
    __syncthreads();
    *(s16x8*)(As + idx) = va;
    *(s16x8*)(Bs + idx) = vb0;
    *(s16x8*)(Bs + idx + 2048) = vb1;
    __syncthreads();

    s16x8 af[2], bfr[4];
#pragma unroll
    for (int mt = 0; mt < 2; mt++)
      af[mt] = *(const s16x8*)(As + (wr * 32 + mt * 16 + l16) * 32 + quad * 8);
#pragma unroll
    for (int nt = 0; nt < 4; nt++)
      bfr[nt] = *(const s16x8*)(Bs + (wc * 64 + nt * 16 + l16) * 32 + quad * 8);
#pragma unroll
    for (int mt = 0; mt < 2; mt++)
#pragma unroll
      for (int nt = 0; nt < 4; nt++)
        acc[mt][nt] = __builtin_amdgcn_mfma_f32_16x16x32_bf16(af[mt], bfr[nt], acc[mt][nt], 0, 0, 0);
  }

#pragma unroll
  for (int nt = 0; nt < 4; nt++) {
    int c = n0 + wc * 64 + nt * 16 + l16;
    float bias = bqkv[c];
    int which = c >> 9;
    int e = c & 511;
    int h = e >> 6, d = e & 63;
#pragma unroll
    for (int mt = 0; mt < 2; mt++) {
      int mbase = m0 + wr * 32 + mt * 16 + quad * 4;
      int bb = mbase >> 10, t = mbase & 1023;
      int bh = bb * 8 + h;
      if (which == 2) {
        ushort4 pk;
        pk.x = f2b(acc[mt][nt][0] + bias);
        pk.y = f2b(acc[mt][nt][1] + bias);
        pk.z = f2b(acc[mt][nt][2] + bias);
        pk.w = f2b(acc[mt][nt][3] + bias);
        *(ushort4*)(VT + (bh * 64 + d) * 1024 + t) = pk;
      } else {
        ushort_t* dst = (which == 0) ? Qh : Kh;
        float sc = (which == 0) ? 0.125f : 1.0f;
#pragma unroll
        for (int rr = 0; rr < 4; rr++)
          dst[(bh * 1024 + t + rr) * 64 + d] = f2b((acc[mt][nt][rr] + bias) * sc);
      }
    }
  }
}

// ------- attention: no-max softmax, split-4, K+V preload, fast-path tiles -------
// __launch_bounds__(256, 3): ~170-VGPR cap fits the 16 preloaded K/V fragments
// while keeping 3 blocks/CU (12 waves) resident.
__global__ __launch_bounds__(256, 3) void attn_kernel(
    const ushort_t* __restrict__ Qh, const ushort_t* __restrict__ Kh,
    const ushort_t* __restrict__ VT, const float* __restrict__ params,
    ushort_t* __restrict__ Oh)
{
  __shared__ ushort_t Plds[4 * 16 * 72];
  __shared__ float Om[4][16][65];
  __shared__ float lwS[4][16];

  const int tid = threadIdx.x;
  const int lane = tid & 63, w = tid >> 6;
  const int quad = lane >> 4, l16 = lane & 15;
  const int bh = blockIdx.x;
  const int mrow = blockIdx.y * 16;
  ushort_t* Pw = Plds + w * (16 * 72);

  s16x8 aq0 = *(const s16x8*)(Qh + (bh * 1024 + mrow + l16) * 64 + quad * 8);
  s16x8 aq1 = *(const s16x8*)(Qh + (bh * 1024 + mrow + l16) * 64 + 32 + quad * 8);

  float bl[4], br[4], al[4], wl[4], wr2[4], da[4];
  float lo = 1.0e9f, hi = -1.0e9f;
#pragma unroll
  for (int rr = 0; rr < 4; rr++) {
    int row = mrow + quad * 4 + rr;
    const float* pp = params + (bh * 1024 + row) * 6;
    bl[rr] = pp[0]; br[rr] = pp[1]; al[rr] = pp[2];
    wl[rr] = pp[3]; wr2[rr] = pp[4]; da[rr] = pp[5];
    bool empty = (br[rr] < 0.f) || (bl[rr] > 1023.f);
    float lo_r = empty ? 0.f    : fmaxf(bl[rr], 0.f);
    float hi_r = empty ? 1023.f : fminf(br[rr], 1023.f);
    lo = fminf(lo, lo_r); hi = fmaxf(hi, hi_r);
  }
  lo = fminf(lo, __shfl_xor(lo, 16));
  lo = fminf(lo, __shfl_xor(lo, 32));
  hi = fmaxf(hi, __shfl_xor(hi, 16));
  hi = fmaxf(hi, __shfl_xor(hi, 32));
  const int tlo = ((int)lo) >> 6, thi = ((int)hi) >> 6;

  float lr[4] = {0.f, 0.f, 0.f, 0.f};
  f32x4 Oacc[4];
#pragma unroll
  for (int nt = 0; nt < 4; nt++) Oacc[nt] = f32x4{0.f, 0.f, 0.f, 0.f};

  for (int tt = tlo + w; tt <= thi; tt += 4) {
    const int r0 = tt * 64;

    s16x8 bk0[4], bk1[4], bv0[4], bv1[4];
#pragma unroll
    for (int nt = 0; nt < 4; nt++) {
      const ushort_t* kp = Kh + (bh * 1024 + r0 + nt * 16 + l16) * 64 + quad * 8;
      bk0[nt] = *(const s16x8*)(kp);
      bk1[nt] = *(const s16x8*)(kp + 32);
    }
#pragma unroll
    for (int nt = 0; nt < 4; nt++) {
      const ushort_t* vp = VT + (bh * 64 + nt * 16 + l16) * 1024 + r0 + quad * 8;
      bv0[nt] = *(const s16x8*)(vp);
      bv1[nt] = *(const s16x8*)(vp + 32);
    }

    f32x4 S[4];
#pragma unroll
    for (int nt = 0; nt < 4; nt++) {
      f32x4 z = {0.f, 0.f, 0.f, 0.f};
      z = __builtin_amdgcn_mfma_f32_16x16x32_bf16(aq0, bk0[nt], z, 0, 0, 0);
      z = __builtin_amdgcn_mfma_f32_16x16x32_bf16(aq1, bk1[nt], z, 0, 0, 0);
      S[nt] = z;
    }

    // Fast path: tile strictly interior to (bl,br) for ALL 16 rows and
    // contains no anchor columns {al, al+1} -> wgt == 1 and no masking,
    // so p = exp(s) exactly. Wave-uniform branch via __all.
    const float r0f = (float)r0, r1f = (float)(r0 + 63);
    bool fastb = true;
#pragma unroll
    for (int rr = 0; rr < 4; rr++) {
      bool f = (bl[rr] < r0f) && (br[rr] > r1f) &&
               ((al[rr] + 1.f < r0f) || (al[rr] > r1f));
      fastb = fastb && f;
    }
    if (__all((int)fastb)) {
#pragma unroll
      for (int nt = 0; nt < 4; nt++)
#pragma unroll
        for (int rr = 0; rr < 4; rr++) {
          float p = __expf(S[nt][rr]);
          lr[rr] += p;
          S[nt][rr] = p;
        }
    } else {
#pragma unroll
      for (int nt = 0; nt < 4; nt++) {
        float cf = (float)(r0 + nt * 16 + l16);
#pragma unroll
        for (int rr = 0; rr < 4; rr++) {
          float s = S[nt][rr];   // includes 0.125 via Qh pre-scale
          float wgt = 1.f;
          wgt += (cf == bl[rr]) ? wl[rr] : 0.f;
          wgt += (cf == br[rr]) ? wr2[rr] : 0.f;
          wgt += (cf == al[rr] + 1.f) ? da[rr] : 0.f;
          wgt += (cf == al[rr]) ? (1.f - da[rr]) : 0.f;
          s *= wgt;
          s = (cf < bl[rr] || cf > br[rr]) ? -30.f : s;
          float p = __expf(s);
          lr[rr] += p;
          S[nt][rr] = p;
        }
      }
    }

    // P (C-layout) -> wave-private LDS -> A-operand layout (HW bf16 cvt).
#pragma unroll
    for (int nt = 0; nt < 4; nt++)
#pragma unroll
      for (int rr = 0; rr < 4; rr++)
        Pw[(quad * 4 + rr) * 72 + nt * 16 + l16] = f2b_hw(S[nt][rr]);

    s16x8 pa0 = *(const s16x8*)(Pw + l16 * 72 + quad * 8);
    s16x8 pa1 = *(const s16x8*)(Pw + l16 * 72 + 32 + quad * 8);

#pragma unroll
    for (int nt = 0; nt < 4; nt++) {
      Oacc[nt] = __builtin_amdgcn_mfma_f32_16x16x32_bf16(pa0, bv0[nt], Oacc[nt], 0, 0, 0);
      Oacc[nt] = __builtin_amdgcn_mfma_f32_16x16x32_bf16(pa1, bv1[nt], Oacc[nt], 0, 0, 0);
    }
  }

  // one row-sum reduction after the whole loop
#pragma unroll
  for (int mask = 1; mask < 16; mask <<= 1)
#pragma unroll
    for (int rr = 0; rr < 4; rr++) lr[rr] += __shfl_xor(lr[rr], mask);

#pragma unroll
  for (int nt = 0; nt < 4; nt++)
#pragma unroll
    for (int rr = 0; rr < 4; rr++)
      Om[w][quad * 4 + rr][nt * 16 + l16] = Oacc[nt][rr];
  if (l16 == 0) {
#pragma unroll
    for (int rr = 0; rr < 4; rr++) lwS[w][quad * 4 + rr] = lr[rr];
  }
  __syncthreads();

  // merge 4 partials (fixed m=0 -> plain sums)
  {
    const int col = tid & 63;
    const int rbase = (tid >> 6) * 4;
    const int bb = bh >> 3, h = bh & 7;
#pragma unroll
    for (int k = 0; k < 4; k++) {
      int r = rbase + k;
      float lg = lwS[0][r] + lwS[1][r] + lwS[2][r] + lwS[3][r];
      float o  = Om[0][r][col] + Om[1][r][col] + Om[2][r][col] + Om[3][r][col];
      int t = mrow + r;
      Oh[((bb << 10) + t) * 512 + h * 64 + col] = f2b_hw(o / lg);
    }
  }
}

// ------- out GEMM: 64x64 tiles, grid (8,32)=256 blocks -------
__global__ __launch_bounds__(256) void out_gemm_kernel(
    const ushort_t* __restrict__ Oh, const ushort_t* __restrict__ WT,
    const float* __restrict__ bout, float* __restrict__ outp)
{
  __shared__ ushort_t As[64 * 32];
  __shared__ ushort_t Bs[64 * 32];
  const int tid = threadIdx.x;
  const int lane = tid & 63, w = tid >> 6;
  const int wr = w >> 1, wc = w & 1;          // wave tile 32x32
  const int quad = lane >> 4, l16 = lane & 15;
  const int m0 = blockIdx.y * 64, n0 = blockIdx.x * 64;

  f32x4 acc[2][2];
#pragma unroll
  for (int i = 0; i < 2; i++)
#pragma unroll
    for (int j = 0; j < 2; j++) acc[i][j] = f32x4{0.f, 0.f, 0.f, 0.f};

  const int idx = tid * 8;
  const int ra = idx >> 5, ca = idx & 31;

  for (int k0 = 0; k0 < 512; k0 += 32) {
    s16x8 va = *(const s16x8*)(Oh + (m0 + ra) * 512 + k0 + ca);
    s16x8 vb = *(const s16x8*)(WT + (n0 + ra) * 512 + k0 + ca);
    __syncthreads();
    *(s16x8*)(As + idx) = va;
    *(s16x8*)(Bs + idx) = vb;
    __syncthreads();

    s16x8 af[2], bfr[2];
#pragma unroll
    for (int mt = 0; mt < 2; mt++)
      af[mt] = *(const s16x8*)(As + (wr * 32 + mt * 16 + l16) * 32 + quad * 8);
#pragma unroll
    for (int nt = 0; nt < 2; nt++)
      bfr[nt] = *(const s16x8*)(Bs + (wc * 32 + nt * 16 + l16) * 32 + quad * 8);
#pragma unroll
    for (int mt = 0; mt < 2; mt++)
#pragma unroll
      for (int nt = 0; nt < 2; nt++)
        acc[mt][nt] = __builtin_amdgcn_mfma_f32_16x16x32_bf16(af[mt], bfr[nt], acc[mt][nt], 0, 0, 0);
  }

#pragma unroll
  for (int nt = 0; nt < 2; nt++) {
    int c = n0 + wc * 32 + nt * 16 + l16;
    float bias = bout[c];
#pragma unroll
    for (int mt = 0; mt < 2; mt++) {
#pragma unroll
      for (int rr = 0; rr < 4; rr++) {
        int m = m0 + wr * 32 + mt * 16 + quad * 4 + rr;
        outp[m * 512 + c] = acc[mt][nt][rr] + bias;
      }
    }
  }
}

extern "C" void kernel_launch(void* const* d_in, const int* in_sizes, int n_in,
                              void* d_out, int out_size, void* d_ws, size_t ws_size,
                              hipStream_t stream)
{
  const float* x    = (const float*)d_in[0];
  const float* Wqkv = (const float*)d_in[1];
  const float* bqkv = (const float*)d_in[2];
  const float* Wod  = (const float*)d_in[3];
  const float* bod  = (const float*)d_in[4];
  const float* Wout = (const float*)d_in[5];
  const float* bout = (const float*)d_in[6];
  const int* lenp   = (const int*)d_in[7];

  char* ws = (char*)d_ws;
  ushort_t* WqkvT  = (ushort_t*)(ws);                  // 1536x512 bf16
  ushort_t* WoT    = (ushort_t*)(ws + 1572864);        // 512x512 bf16
  ushort_t* xb     = (ushort_t*)(ws + 2097152);        // 2048x512 bf16
  ushort_t* Qh     = (ushort_t*)(ws + 4194304);        // 16x1024x64 bf16 (pre-scaled 0.125)
  ushort_t* Kh     = (ushort_t*)(ws + 6291456);        // 16x1024x64 bf16
  ushort_t* VT     = (ushort_t*)(ws + 8388608);        // 16x64x1024 bf16
  ushort_t* Oh     = (ushort_t*)(ws + 10485760);       // 2048x512 bf16
  float*    Wcomb  = (float*)(ws + 12582912);          // 512x16 f32
  float*    bcomb  = (float*)(ws + 12615680);          // 16 f32
  float*    params = (float*)(ws + 12615744);          // 16x1024x6 f32

  prep_kernel<<<385, 256, 0, stream>>>(Wqkv, bqkv, Wod, bod, Wout, WqkvT, WoT, Wcomb, bcomb);
  od_kernel<<<512, 256, 0, stream>>>(x, Wcomb, bcomb, lenp, params, xb);
  qkv_gemm_kernel<<<dim3(12, 32), 256, 0, stream>>>(xb, WqkvT, bqkv, Qh, Kh, VT);
  attn_kernel<<<dim3(16, 64), 256, 0, stream>>>(Qh, Kh, VT, params, Oh);
  out_gemm_kernel<<<dim3(8, 32), 256, 0, stream>>>(Oh, WoT, bout, (float*)d_out);
}

// Round 11
// 129.902 us; speedup vs baseline: 1.0746x; 1.0746x over previous
//
#include <hip/hip_runtime.h>

typedef unsigned short ushort_t;
typedef short s16x8 __attribute__((ext_vector_type(8)));   // bf16 frag vector
typedef float f32x4 __attribute__((ext_vector_type(4)));

#define DEVINL __device__ __forceinline__

DEVINL ushort_t f2b(float f) {           // fp32 -> bf16 RNE
  union { float f; unsigned int u; } v; v.f = f;
  unsigned int r = (v.u + 0x7fffu + ((v.u >> 16) & 1u)) >> 16;
  return (ushort_t)r;
}

DEVINL ushort_t f2b_hw(float f) {        // fp32 -> bf16 via HW v_cvt (RNE)
  union { __bf16 h; ushort_t u; } cv;
  cv.h = (__bf16)f;
  return cv.u;
}

// ---------- prep: fused {Wqkv transpose, Wout transpose, fold} ----------
__global__ __launch_bounds__(256) void prep_kernel(
    const float* __restrict__ Wqkv, const float* __restrict__ bq,
    const float* __restrict__ Wod, const float* __restrict__ bod,
    const float* __restrict__ Wout,
    ushort_t* __restrict__ WqkvT, ushort_t* __restrict__ WoT,
    float* __restrict__ Wcomb, float* __restrict__ bcomb)
{
  __shared__ ushort_t tile[64 * 72];
  const int b = blockIdx.x;
  const int tid = threadIdx.x;

  if (b < 256) {
    const float* in;
    ushort_t* out;
    int N, bx, by;
    if (b < 192) { in = Wqkv; out = WqkvT; N = 1536; bx = b % 24; by = b / 24; }
    else         { in = Wout; out = WoT;   N = 512;  bx = (b - 192) % 8; by = (b - 192) / 8; }
    const int K = 512;
    const int n0 = bx * 64, k0 = by * 64;
    const int cr = tid >> 4;
    const int cc = (tid & 15) * 4;
#pragma unroll
    for (int p = 0; p < 4; p++) {
      int k = k0 + p * 16 + cr;
      float4 v = *(const float4*)(in + k * N + n0 + cc);
      ushort4 o; o.x = f2b(v.x); o.y = f2b(v.y); o.z = f2b(v.z); o.w = f2b(v.w);
      *(ushort4*)(tile + (p * 16 + cr) * 72 + cc) = o;
    }
    __syncthreads();
#pragma unroll
    for (int p = 0; p < 4; p++) {
      int n = n0 + p * 16 + cr;
      ushort4 v;
      v.x = tile[(cc + 0) * 72 + p * 16 + cr];
      v.y = tile[(cc + 1) * 72 + p * 16 + cr];
      v.z = tile[(cc + 2) * 72 + p * 16 + cr];
      v.w = tile[(cc + 3) * 72 + p * 16 + cr];
      *(ushort4*)(out + n * K + k0 + cc) = v;
    }
    return;
  }

  // fold: one wave per c-row
  const int w = tid >> 6, lane = tid & 63;
  const int c = (b - 256) * 4 + w;
  if (c > 512) return;
  float a[8];
  const float* src = (c < 512) ? (Wqkv + c * 1536 + lane * 8) : (bq + lane * 8);
  float4 a0 = *(const float4*)(src);
  float4 a1 = *(const float4*)(src + 4);
  a[0]=a0.x; a[1]=a0.y; a[2]=a0.z; a[3]=a0.w;
  a[4]=a1.x; a[5]=a1.y; a[6]=a1.z; a[7]=a1.w;

  float s[16];
#pragma unroll
  for (int j = 0; j < 16; j++) s[j] = 0.f;
#pragma unroll
  for (int i = 0; i < 8; i++) {
    const float* wp = Wod + (lane * 8 + i) * 16;
#pragma unroll
    for (int j = 0; j < 16; j++) s[j] += a[i] * wp[j];
  }
#pragma unroll
  for (int mask = 1; mask < 64; mask <<= 1)
#pragma unroll
    for (int j = 0; j < 16; j++) s[j] += __shfl_xor(s[j], mask);

  if (lane < 16) {
    if (c < 512) Wcomb[c * 16 + lane] = s[lane];
    else         bcomb[lane] = s[lane] + bod[lane];
  }
}

// ---------------- od (fp32) + x->bf16 conversion fused ----------------
__global__ __launch_bounds__(256) void od_kernel(
    const float* __restrict__ x, const float* __restrict__ Wcomb,
    const float* __restrict__ bcomb, const int* __restrict__ lenp,
    float* __restrict__ params, ushort_t* __restrict__ xb)
{
  const int w = threadIdx.x >> 6, lane = threadIdx.x & 63;
  const int m = blockIdx.x * 4 + w;   // 0..2047
  int li = lenp[0];
  float len = (li > 0 && li < 1048576) ? (float)li : 1024.0f;

  const float* qp = x + m * 512 + lane * 8;
  float q[8];
  float4 qa = *(const float4*)(qp);
  float4 qb = *(const float4*)(qp + 4);
  q[0]=qa.x; q[1]=qa.y; q[2]=qa.z; q[3]=qa.w;
  q[4]=qb.x; q[5]=qb.y; q[6]=qb.z; q[7]=qb.w;

  s16x8 ov;
#pragma unroll
  for (int i = 0; i < 8; i++) ov[i] = (short)f2b(q[i]);
  *(s16x8*)(xb + m * 512 + lane * 8) = ov;

  float s[16];
#pragma unroll
  for (int j = 0; j < 16; j++) s[j] = 0.f;
#pragma unroll
  for (int i = 0; i < 8; i++) {
    const float* wp = Wcomb + (lane * 8 + i) * 16;
#pragma unroll
    for (int j = 0; j < 16; j++) s[j] += q[i] * wp[j];
  }
#pragma unroll
  for (int mask = 1; mask < 64; mask <<= 1)
#pragma unroll
    for (int j = 0; j < 16; j++) s[j] += __shfl_xor(s[j], mask);

  if (lane < 8) {
    int h = lane;
    int bb = m >> 10, t = m & 1023;
    float odo = s[h] + bcomb[h];
    float odd = s[8 + h] + bcomb[8 + h];
    float offset = tanhf(odo) * len;
    float dur = len / (1.f + expf(-odd));
    float anchor = (float)t + offset;
    float start = anchor - dur, end = anchor + dur;
    float bl = floorf(start), br = ceilf(end);
    float al = floorf(anchor);
    float da = anchor - al;
    float* pp = params + ((bb * 8 + h) * 1024 + t) * 6;
    pp[0] = bl; pp[1] = br; pp[2] = al;
    pp[3] = bl - start; pp[4] = end - br; pp[5] = da;
  }
}

// ------- qkv GEMM: 64x128 tiles, grid (12,32); Q pre-scaled 0.125; VT direct -------
__global__ __launch_bounds__(256) void qkv_gemm_kernel(
    const ushort_t* __restrict__ xb, const ushort_t* __restrict__ WT,
    const float* __restrict__ bqkv,
    ushort_t* __restrict__ Qh, ushort_t* __restrict__ Kh, ushort_t* __restrict__ VT)
{
  __shared__ ushort_t As[64 * 32];
  __shared__ ushort_t Bs[128 * 32];
  const int tid = threadIdx.x;
  const int lane = tid & 63, w = tid >> 6;
  const int wr = w >> 1, wc = w & 1;          // wave tile 32x64
  const int quad = lane >> 4, l16 = lane & 15;
  const int m0 = blockIdx.y * 64, n0 = blockIdx.x * 128;

  f32x4 acc[2][4];
#pragma unroll
  for (int i = 0; i < 2; i++)
#pragma unroll
    for (int j = 0; j < 4; j++) acc[i][j] = f32x4{0.f, 0.f, 0.f, 0.f};

  const int idx = tid * 8;
  const int ra = idx >> 5, ca = idx & 31;
  const int rb1 = (idx + 2048) >> 5, cb1 = (idx + 2048) & 31;

  for (int k0 = 0; k0 < 512; k0 += 32) {
    s16x8 va  = *(const s16x8*)(xb + (m0 + ra) * 512 + k0 + ca);
    s16x8 vb0 = *(const s16x8*)(WT + (n0 + ra) * 512 + k0 + ca);
    s16x8 vb1 = *(const s16x8*)(WT + (n0 + rb1) * 512 + k0 + cb1);
    __syncthreads();
    *(s16x8*)(As + idx) = va;
    *(s16x8*)(Bs + idx) = vb0;
    *(s16x8*)(Bs + idx + 2048) = vb1;
    __syncthreads();

    s16x8 af[2], bfr[4];
#pragma unroll
    for (int mt = 0; mt < 2; mt++)
      af[mt] = *(const s16x8*)(As + (wr * 32 + mt * 16 + l16) * 32 + quad * 8);
#pragma unroll
    for (int nt = 0; nt < 4; nt++)
      bfr[nt] = *(const s16x8*)(Bs + (wc * 64 + nt * 16 + l16) * 32 + quad * 8);
#pragma unroll
    for (int mt = 0; mt < 2; mt++)
#pragma unroll
      for (int nt = 0; nt < 4; nt++)
        acc[mt][nt] = __builtin_amdgcn_mfma_f32_16x16x32_bf16(af[mt], bfr[nt], acc[mt][nt], 0, 0, 0);
  }

#pragma unroll
  for (int nt = 0; nt < 4; nt++) {
    int c = n0 + wc * 64 + nt * 16 + l16;
    float bias = bqkv[c];
    int which = c >> 9;
    int e = c & 511;
    int h = e >> 6, d = e & 63;
#pragma unroll
    for (int mt = 0; mt < 2; mt++) {
      int mbase = m0 + wr * 32 + mt * 16 + quad * 4;
      int bb = mbase >> 10, t = mbase & 1023;
      int bh = bb * 8 + h;
      if (which == 2) {
        ushort4 pk;
        pk.x = f2b(acc[mt][nt][0] + bias);
        pk.y = f2b(acc[mt][nt][1] + bias);
        pk.z = f2b(acc[mt][nt][2] + bias);
        pk.w = f2b(acc[mt][nt][3] + bias);
        *(ushort4*)(VT + (bh * 64 + d) * 1024 + t) = pk;
      } else {
        ushort_t* dst = (which == 0) ? Qh : Kh;
        float sc = (which == 0) ? 0.125f : 1.0f;
#pragma unroll
        for (int rr = 0; rr < 4; rr++)
          dst[(bh * 1024 + t + rr) * 64 + d] = f2b((acc[mt][nt][rr] + bias) * sc);
      }
    }
  }
}

// ------- attention: cooperative K/V LDS staging, waves split K-columns -------
// Block = (bh, 16 Q-rows). All 4 waves iterate the SAME tile list (union window);
// each tile's K(64x64) + V(64x64) staged ONCE into padded LDS with coalesced
// 128B-contiguous loads (software-pipelined: next tile's loads issue before
// current tile's compute). Wave w owns K-columns [w*16, w*16+16). This cuts
// L1 line-requests 4x vs fragment-direct loads (rounds 3-10: ~10k cyc/tile
// came from 16 lines/instr x 16 instr x 4 independent waves).
__global__ __launch_bounds__(256, 3) void attn_kernel(
    const ushort_t* __restrict__ Qh, const ushort_t* __restrict__ Kh,
    const ushort_t* __restrict__ VT, const float* __restrict__ params,
    ushort_t* __restrict__ Oh)
{
  __shared__ ushort_t Kt[64 * 72 + 32];    // K tile: row t (0..63), stride 72
  __shared__ ushort_t Vt[64 * 72 + 96];    // V tile: row d (0..63), stride 72 (+guard)
  __shared__ ushort_t Ps[4][16 * 40];      // per-wave P slab: 16 rows x (32 cols + 8 pad)
  __shared__ float Om[4][16][65];
  __shared__ float lwS[4][16];

  const int tid = threadIdx.x;
  const int lane = tid & 63, w = tid >> 6;
  const int quad = lane >> 4, l16 = lane & 15;
  const int bh = blockIdx.x;
  const int mrow = blockIdx.y * 16;
  ushort_t* Pw = Ps[w];

  // P slab cols 16..31 are a permanent zero pad (PV uses K=32 MFMA with the
  // upper half zeroed) -- init once, wave-private, never rewritten.
#pragma unroll
  for (int rr = 0; rr < 4; rr++)
    Pw[(quad * 4 + rr) * 40 + 16 + l16] = 0;

  s16x8 aq0 = *(const s16x8*)(Qh + (bh * 1024 + mrow + l16) * 64 + quad * 8);
  s16x8 aq1 = *(const s16x8*)(Qh + (bh * 1024 + mrow + l16) * 64 + 32 + quad * 8);

  float bl[4], br[4], al[4], wl[4], wr2[4], da[4];
  float lo = 1.0e9f, hi = -1.0e9f;
#pragma unroll
  for (int rr = 0; rr < 4; rr++) {
    int row = mrow + quad * 4 + rr;
    const float* pp = params + (bh * 1024 + row) * 6;
    bl[rr] = pp[0]; br[rr] = pp[1]; al[rr] = pp[2];
    wl[rr] = pp[3]; wr2[rr] = pp[4]; da[rr] = pp[5];
    bool empty = (br[rr] < 0.f) || (bl[rr] > 1023.f);
    float lo_r = empty ? 0.f    : fmaxf(bl[rr], 0.f);
    float hi_r = empty ? 1023.f : fminf(br[rr], 1023.f);
    lo = fminf(lo, lo_r); hi = fmaxf(hi, hi_r);
  }
  lo = fminf(lo, __shfl_xor(lo, 16));
  lo = fminf(lo, __shfl_xor(lo, 32));
  hi = fmaxf(hi, __shfl_xor(hi, 16));
  hi = fmaxf(hi, __shfl_xor(hi, 32));
  const int tlo = ((int)lo) >> 6, thi = ((int)hi) >> 6;   // wave-uniform, same all waves

  float lr[4] = {0.f, 0.f, 0.f, 0.f};
  f32x4 Oacc[4];
#pragma unroll
  for (int nt = 0; nt < 4; nt++) Oacc[nt] = f32x4{0.f, 0.f, 0.f, 0.f};

  // staging assignment: row = tid>>2 (0..63), seg = (tid&3)*16 elements
  const int srow = tid >> 2, sseg = (tid & 3) * 16;
  const ushort_t* kgb = Kh + (bh * 1024 + srow) * 64 + sseg;        // + r0*64
  const ushort_t* vgb = VT + (bh * 64 + srow) * 1024 + sseg;        // + r0

  // prologue: load first tile into regs
  s16x8 kr0, kr1, vr0, vr1;
  {
    const int r0 = tlo * 64;
    kr0 = *(const s16x8*)(kgb + r0 * 64);
    kr1 = *(const s16x8*)(kgb + r0 * 64 + 8);
    vr0 = *(const s16x8*)(vgb + r0);
    vr1 = *(const s16x8*)(vgb + r0 + 8);
  }

  for (int tt = tlo; tt <= thi; tt++) {
    const int r0 = tt * 64;
    __syncthreads();                     // previous tile's LDS reads done
    *(s16x8*)(Kt + srow * 72 + sseg)     = kr0;
    *(s16x8*)(Kt + srow * 72 + sseg + 8) = kr1;
    *(s16x8*)(Vt + srow * 72 + sseg)     = vr0;
    *(s16x8*)(Vt + srow * 72 + sseg + 8) = vr1;
    __syncthreads();                     // staging visible to all waves

    if (tt + 1 <= thi) {                 // issue next tile's loads (hidden by compute)
      const int r1 = (tt + 1) * 64;
      kr0 = *(const s16x8*)(kgb + r1 * 64);
      kr1 = *(const s16x8*)(kgb + r1 * 64 + 8);
      vr0 = *(const s16x8*)(vgb + r1);
      vr1 = *(const s16x8*)(vgb + r1 + 8);
    }

    // QK^T for this wave's 16 K-columns (rows w*16+l16 of the K tile)
    s16x8 bk0 = *(const s16x8*)(Kt + (w * 16 + l16) * 72 + quad * 8);
    s16x8 bk1 = *(const s16x8*)(Kt + (w * 16 + l16) * 72 + 32 + quad * 8);
    f32x4 S = {0.f, 0.f, 0.f, 0.f};
    S = __builtin_amdgcn_mfma_f32_16x16x32_bf16(aq0, bk0, S, 0, 0, 0);
    S = __builtin_amdgcn_mfma_f32_16x16x32_bf16(aq1, bk1, S, 0, 0, 0);

    // softmax weights/mask for column cf (4 rows per lane)
    const float cf = (float)(r0 + w * 16 + l16);
    const float c0f = (float)(r0 + w * 16), c1f = c0f + 15.f;
    bool fastb = true;
#pragma unroll
    for (int rr = 0; rr < 4; rr++) {
      bool f = (bl[rr] < c0f) && (br[rr] > c1f) &&
               ((al[rr] + 1.f < c0f) || (al[rr] > c1f));
      fastb = fastb && f;
    }
    float p4[4];
    if (__all((int)fastb)) {
#pragma unroll
      for (int rr = 0; rr < 4; rr++) {
        float p = __expf(S[rr]);
        lr[rr] += p;
        p4[rr] = p;
      }
    } else {
#pragma unroll
      for (int rr = 0; rr < 4; rr++) {
        float s = S[rr];                 // includes 0.125 via Qh pre-scale
        float wgt = 1.f;
        wgt += (cf == bl[rr]) ? wl[rr] : 0.f;
        wgt += (cf == br[rr]) ? wr2[rr] : 0.f;
        wgt += (cf == al[rr] + 1.f) ? da[rr] : 0.f;
        wgt += (cf == al[rr]) ? (1.f - da[rr]) : 0.f;
        s *= wgt;
        s = (cf < bl[rr] || cf > br[rr]) ? -30.f : s;
        float p = __expf(s);
        lr[rr] += p;
        p4[rr] = p;
      }
    }

    // P (C-layout) -> wave-private slab cols 0..15 (16..31 stay zero)
#pragma unroll
    for (int rr = 0; rr < 4; rr++)
      Pw[(quad * 4 + rr) * 40 + l16] = f2b_hw(p4[rr]);

    // PV: A = P rows (m=l16, k=quad*8+j over 32 cols, upper 16 zero);
    // B = V (k=t_local=w*16+quad*8+j [j>=16 reads x0 garbage], n=d=nt*16+l16)
    s16x8 pa = *(const s16x8*)(Pw + l16 * 40 + quad * 8);
#pragma unroll
    for (int nt = 0; nt < 4; nt++) {
      s16x8 bv = *(const s16x8*)(Vt + (nt * 16 + l16) * 72 + w * 16 + quad * 8);
      Oacc[nt] = __builtin_amdgcn_mfma_f32_16x16x32_bf16(pa, bv, Oacc[nt], 0, 0, 0);
    }
  }

  // per-wave row sums (lane holds partial for its column position)
#pragma unroll
  for (int mask = 1; mask < 16; mask <<= 1)
#pragma unroll
    for (int rr = 0; rr < 4; rr++) lr[rr] += __shfl_xor(lr[rr], mask);

#pragma unroll
  for (int nt = 0; nt < 4; nt++)
#pragma unroll
    for (int rr = 0; rr < 4; rr++)
      Om[w][quad * 4 + rr][nt * 16 + l16] = Oacc[nt][rr];
  if (l16 == 0) {
#pragma unroll
    for (int rr = 0; rr < 4; rr++) lwS[w][quad * 4 + rr] = lr[rr];
  }
  __syncthreads();

  // merge 4 K-column-group partials (fixed m=0 -> plain sums)
  {
    const int col = tid & 63;
    const int rbase = (tid >> 6) * 4;
    const int bb = bh >> 3, h = bh & 7;
#pragma unroll
    for (int k = 0; k < 4; k++) {
      int r = rbase + k;
      float lg = lwS[0][r] + lwS[1][r] + lwS[2][r] + lwS[3][r];
      float o  = Om[0][r][col] + Om[1][r][col] + Om[2][r][col] + Om[3][r][col];
      int t = mrow + r;
      Oh[((bb << 10) + t) * 512 + h * 64 + col] = f2b_hw(o / lg);
    }
  }
}

// ------- out GEMM: 64x64 tiles, grid (8,32)=256 blocks -------
__global__ __launch_bounds__(256) void out_gemm_kernel(
    const ushort_t* __restrict__ Oh, const ushort_t* __restrict__ WT,
    const float* __restrict__ bout, float* __restrict__ outp)
{
  __shared__ ushort_t As[64 * 32];
  __shared__ ushort_t Bs[64 * 32];
  const int tid = threadIdx.x;
  const int lane = tid & 63, w = tid >> 6;
  const int wr = w >> 1, wc = w & 1;          // wave tile 32x32
  const int quad = lane >> 4, l16 = lane & 15;
  const int m0 = blockIdx.y * 64, n0 = blockIdx.x * 64;

  f32x4 acc[2][2];
#pragma unroll
  for (int i = 0; i < 2; i++)
#pragma unroll
    for (int j = 0; j < 2; j++) acc[i][j] = f32x4{0.f, 0.f, 0.f, 0.f};

  const int idx = tid * 8;
  const int ra = idx >> 5, ca = idx & 31;

  for (int k0 = 0; k0 < 512; k0 += 32) {
    s16x8 va = *(const s16x8*)(Oh + (m0 + ra) * 512 + k0 + ca);
    s16x8 vb = *(const s16x8*)(WT + (n0 + ra) * 512 + k0 + ca);
    __syncthreads();
    *(s16x8*)(As + idx) = va;
    *(s16x8*)(Bs + idx) = vb;
    __syncthreads();

    s16x8 af[2], bfr[2];
#pragma unroll
    for (int mt = 0; mt < 2; mt++)
      af[mt] = *(const s16x8*)(As + (wr * 32 + mt * 16 + l16) * 32 + quad * 8);
#pragma unroll
    for (int nt = 0; nt < 2; nt++)
      bfr[nt] = *(const s16x8*)(Bs + (wc * 32 + nt * 16 + l16) * 32 + quad * 8);
#pragma unroll
    for (int mt = 0; mt < 2; mt++)
#pragma unroll
      for (int nt = 0; nt < 2; nt++)
        acc[mt][nt] = __builtin_amdgcn_mfma_f32_16x16x32_bf16(af[mt], bfr[nt], acc[mt][nt], 0, 0, 0);
  }

#pragma unroll
  for (int nt = 0; nt < 2; nt++) {
    int c = n0 + wc * 32 + nt * 16 + l16;
    float bias = bout[c];
#pragma unroll
    for (int mt = 0; mt < 2; mt++) {
#pragma unroll
      for (int rr = 0; rr < 4; rr++) {
        int m = m0 + wr * 32 + mt * 16 + quad * 4 + rr;
        outp[m * 512 + c] = acc[mt][nt][rr] + bias;
      }
    }
  }
}

extern "C" void kernel_launch(void* const* d_in, const int* in_sizes, int n_in,
                              void* d_out, int out_size, void* d_ws, size_t ws_size,
                              hipStream_t stream)
{
  const float* x    = (const float*)d_in[0];
  const float* Wqkv = (const float*)d_in[1];
  const float* bqkv = (const float*)d_in[2];
  const float* Wod  = (const float*)d_in[3];
  const float* bod  = (const float*)d_in[4];
  const float* Wout = (const float*)d_in[5];
  const float* bout = (const float*)d_in[6];
  const int* lenp   = (const int*)d_in[7];

  char* ws = (char*)d_ws;
  ushort_t* WqkvT  = (ushort_t*)(ws);                  // 1536x512 bf16
  ushort_t* WoT    = (ushort_t*)(ws + 1572864);        // 512x512 bf16
  ushort_t* xb     = (ushort_t*)(ws + 2097152);        // 2048x512 bf16
  ushort_t* Qh     = (ushort_t*)(ws + 4194304);        // 16x1024x64 bf16 (pre-scaled 0.125)
  ushort_t* Kh     = (ushort_t*)(ws + 6291456);        // 16x1024x64 bf16
  ushort_t* VT     = (ushort_t*)(ws + 8388608);        // 16x64x1024 bf16
  ushort_t* Oh     = (ushort_t*)(ws + 10485760);       // 2048x512 bf16
  float*    Wcomb  = (float*)(ws + 12582912);          // 512x16 f32
  float*    bcomb  = (float*)(ws + 12615680);          // 16 f32
  float*    params = (float*)(ws + 12615744);          // 16x1024x6 f32

  prep_kernel<<<385, 256, 0, stream>>>(Wqkv, bqkv, Wod, bod, Wout, WqkvT, WoT, Wcomb, bcomb);
  od_kernel<<<512, 256, 0, stream>>>(x, Wcomb, bcomb, lenp, params, xb);
  qkv_gemm_kernel<<<dim3(12, 32), 256, 0, stream>>>(xb, WqkvT, bqkv, Qh, Kh, VT);
  attn_kernel<<<dim3(16, 64), 256, 0, stream>>>(Qh, Kh, VT, params, Oh);
  out_gemm_kernel<<<dim3(8, 32), 256, 0, stream>>>(Oh, WoT, bout, (float*)d_out);
}

// Round 12
// 129.349 us; speedup vs baseline: 1.0792x; 1.0043x over previous
//
#include <hip/hip_runtime.h>

typedef unsigned short ushort_t;
typedef short s16x8 __attribute__((ext_vector_type(8)));   // bf16 frag vector
typedef float f32x4 __attribute__((ext_vector_type(4)));

#define DEVINL __device__ __forceinline__

DEVINL ushort_t f2b(float f) {           // fp32 -> bf16 RNE
  union { float f; unsigned int u; } v; v.f = f;
  unsigned int r = (v.u + 0x7fffu + ((v.u >> 16) & 1u)) >> 16;
  return (ushort_t)r;
}

DEVINL ushort_t f2b_hw(float f) {        // fp32 -> bf16 via HW v_cvt (RNE)
  union { __bf16 h; ushort_t u; } cv;
  cv.h = (__bf16)f;
  return cv.u;
}

// ---------- prep: fused {Wqkv transpose, Wout transpose, fold} ----------
__global__ __launch_bounds__(256) void prep_kernel(
    const float* __restrict__ Wqkv, const float* __restrict__ bq,
    const float* __restrict__ Wod, const float* __restrict__ bod,
    const float* __restrict__ Wout,
    ushort_t* __restrict__ WqkvT, ushort_t* __restrict__ WoT,
    float* __restrict__ Wcomb, float* __restrict__ bcomb)
{
  __shared__ ushort_t tile[64 * 72];
  const int b = blockIdx.x;
  const int tid = threadIdx.x;

  if (b < 256) {
    const float* in;
    ushort_t* out;
    int N, bx, by;
    if (b < 192) { in = Wqkv; out = WqkvT; N = 1536; bx = b % 24; by = b / 24; }
    else         { in = Wout; out = WoT;   N = 512;  bx = (b - 192) % 8; by = (b - 192) / 8; }
    const int K = 512;
    const int n0 = bx * 64, k0 = by * 64;
    const int cr = tid >> 4;
    const int cc = (tid & 15) * 4;
#pragma unroll
    for (int p = 0; p < 4; p++) {
      int k = k0 + p * 16 + cr;
      float4 v = *(const float4*)(in + k * N + n0 + cc);
      ushort4 o; o.x = f2b(v.x); o.y = f2b(v.y); o.z = f2b(v.z); o.w = f2b(v.w);
      *(ushort4*)(tile + (p * 16 + cr) * 72 + cc) = o;
    }
    __syncthreads();
#pragma unroll
    for (int p = 0; p < 4; p++) {
      int n = n0 + p * 16 + cr;
      ushort4 v;
      v.x = tile[(cc + 0) * 72 + p * 16 + cr];
      v.y = tile[(cc + 1) * 72 + p * 16 + cr];
      v.z = tile[(cc + 2) * 72 + p * 16 + cr];
      v.w = tile[(cc + 3) * 72 + p * 16 + cr];
      *(ushort4*)(out + n * K + k0 + cc) = v;
    }
    return;
  }

  // fold: one wave per c-row
  const int w = tid >> 6, lane = tid & 63;
  const int c = (b - 256) * 4 + w;
  if (c > 512) return;
  float a[8];
  const float* src = (c < 512) ? (Wqkv + c * 1536 + lane * 8) : (bq + lane * 8);
  float4 a0 = *(const float4*)(src);
  float4 a1 = *(const float4*)(src + 4);
  a[0]=a0.x; a[1]=a0.y; a[2]=a0.z; a[3]=a0.w;
  a[4]=a1.x; a[5]=a1.y; a[6]=a1.z; a[7]=a1.w;

  float s[16];
#pragma unroll
  for (int j = 0; j < 16; j++) s[j] = 0.f;
#pragma unroll
  for (int i = 0; i < 8; i++) {
    const float* wp = Wod + (lane * 8 + i) * 16;
#pragma unroll
    for (int j = 0; j < 16; j++) s[j] += a[i] * wp[j];
  }
#pragma unroll
  for (int mask = 1; mask < 64; mask <<= 1)
#pragma unroll
    for (int j = 0; j < 16; j++) s[j] += __shfl_xor(s[j], mask);

  if (lane < 16) {
    if (c < 512) Wcomb[c * 16 + lane] = s[lane];
    else         bcomb[lane] = s[lane] + bod[lane];
  }
}

// ---------------- od (fp32) + x->bf16 conversion fused ----------------
__global__ __launch_bounds__(256) void od_kernel(
    const float* __restrict__ x, const float* __restrict__ Wcomb,
    const float* __restrict__ bcomb, const int* __restrict__ lenp,
    float* __restrict__ params, ushort_t* __restrict__ xb)
{
  const int w = threadIdx.x >> 6, lane = threadIdx.x & 63;
  const int m = blockIdx.x * 4 + w;   // 0..2047
  int li = lenp[0];
  float len = (li > 0 && li < 1048576) ? (float)li : 1024.0f;

  const float* qp = x + m * 512 + lane * 8;
  float q[8];
  float4 qa = *(const float4*)(qp);
  float4 qb = *(const float4*)(qp + 4);
  q[0]=qa.x; q[1]=qa.y; q[2]=qa.z; q[3]=qa.w;
  q[4]=qb.x; q[5]=qb.y; q[6]=qb.z; q[7]=qb.w;

  s16x8 ov;
#pragma unroll
  for (int i = 0; i < 8; i++) ov[i] = (short)f2b(q[i]);
  *(s16x8*)(xb + m * 512 + lane * 8) = ov;

  float s[16];
#pragma unroll
  for (int j = 0; j < 16; j++) s[j] = 0.f;
#pragma unroll
  for (int i = 0; i < 8; i++) {
    const float* wp = Wcomb + (lane * 8 + i) * 16;
#pragma unroll
    for (int j = 0; j < 16; j++) s[j] += q[i] * wp[j];
  }
#pragma unroll
  for (int mask = 1; mask < 64; mask <<= 1)
#pragma unroll
    for (int j = 0; j < 16; j++) s[j] += __shfl_xor(s[j], mask);

  if (lane < 8) {
    int h = lane;
    int bb = m >> 10, t = m & 1023;
    float odo = s[h] + bcomb[h];
    float odd = s[8 + h] + bcomb[8 + h];
    float offset = tanhf(odo) * len;
    float dur = len / (1.f + expf(-odd));
    float anchor = (float)t + offset;
    float start = anchor - dur, end = anchor + dur;
    float bl = floorf(start), br = ceilf(end);
    float al = floorf(anchor);
    float da = anchor - al;
    float* pp = params + ((bb * 8 + h) * 1024 + t) * 6;
    pp[0] = bl; pp[1] = br; pp[2] = al;
    pp[3] = bl - start; pp[4] = end - br; pp[5] = da;
  }
}

// ------- qkv GEMM: 64x128 tiles, grid (12,32); Q pre-scaled 0.125; VT direct -------
__global__ __launch_bounds__(256) void qkv_gemm_kernel(
    const ushort_t* __restrict__ xb, const ushort_t* __restrict__ WT,
    const float* __restrict__ bqkv,
    ushort_t* __restrict__ Qh, ushort_t* __restrict__ Kh, ushort_t* __restrict__ VT)
{
  __shared__ ushort_t As[64 * 32];
  __shared__ ushort_t Bs[128 * 32];
  const int tid = threadIdx.x;
  const int lane = tid & 63, w = tid >> 6;
  const int wr = w >> 1, wc = w & 1;          // wave tile 32x64
  const int quad = lane >> 4, l16 = lane & 15;
  const int m0 = blockIdx.y * 64, n0 = blockIdx.x * 128;

  f32x4 acc[2][4];
#pragma unroll
  for (int i = 0; i < 2; i++)
#pragma unroll
    for (int j = 0; j < 4; j++) acc[i][j] = f32x4{0.f, 0.f, 0.f, 0.f};

  const int idx = tid * 8;
  const int ra = idx >> 5, ca = idx & 31;
  const int rb1 = (idx + 2048) >> 5, cb1 = (idx + 2048) & 31;

  for (int k0 = 0; k0 < 512; k0 += 32) {
    s16x8 va  = *(const s16x8*)(xb + (m0 + ra) * 512 + k0 + ca);
    s16x8 vb0 = *(const s16x8*)(WT + (n0 + ra) * 512 + k0 + ca);
    s16x8 vb1 = *(const s16x8*)(WT + (n0 + rb1) * 512 + k0 + cb1);
    __syncthreads();
    *(s16x8*)(As + idx) = va;
    *(s16x8*)(Bs + idx) = vb0;
    *(s16x8*)(Bs + idx + 2048) = vb1;
    __syncthreads();

    s16x8 af[2], bfr[4];
#pragma unroll
    for (int mt = 0; mt < 2; mt++)
      af[mt] = *(const s16x8*)(As + (wr * 32 + mt * 16 + l16) * 32 + quad * 8);
#pragma unroll
    for (int nt = 0; nt < 4; nt++)
      bfr[nt] = *(const s16x8*)(Bs + (wc * 64 + nt * 16 + l16) * 32 + quad * 8);
#pragma unroll
    for (int mt = 0; mt < 2; mt++)
#pragma unroll
      for (int nt = 0; nt < 4; nt++)
        acc[mt][nt] = __builtin_amdgcn_mfma_f32_16x16x32_bf16(af[mt], bfr[nt], acc[mt][nt], 0, 0, 0);
  }

#pragma unroll
  for (int nt = 0; nt < 4; nt++) {
    int c = n0 + wc * 64 + nt * 16 + l16;
    float bias = bqkv[c];
    int which = c >> 9;
    int e = c & 511;
    int h = e >> 6, d = e & 63;
#pragma unroll
    for (int mt = 0; mt < 2; mt++) {
      int mbase = m0 + wr * 32 + mt * 16 + quad * 4;
      int bb = mbase >> 10, t = mbase & 1023;
      int bh = bb * 8 + h;
      if (which == 2) {
        ushort4 pk;
        pk.x = f2b(acc[mt][nt][0] + bias);
        pk.y = f2b(acc[mt][nt][1] + bias);
        pk.z = f2b(acc[mt][nt][2] + bias);
        pk.w = f2b(acc[mt][nt][3] + bias);
        *(ushort4*)(VT + (bh * 64 + d) * 1024 + t) = pk;
      } else {
        ushort_t* dst = (which == 0) ? Qh : Kh;
        float sc = (which == 0) ? 0.125f : 1.0f;
#pragma unroll
        for (int rr = 0; rr < 4; rr++)
          dst[(bh * 1024 + t + rr) * 64 + d] = f2b((acc[mt][nt][rr] + bias) * sc);
      }
    }
  }
}

// ------- attention v2: 32 Q-rows/block, 2x2 wave layout, ping-pong K/V LDS -------
// Block = (bh, 32 Q-rows), 512 blocks. Wave (wr,wc): rows wr*16..+15, K-cols
// wc*32..+31 of each 64-col tile. K/V staged once per block per tile into
// ping-pong buffers (ONE barrier per tile). P is an exact 16x32 A-operand
// (full K=32 PV MFMA, no zero pad). Merge scratch overlays dead staging LDS.
__global__ __launch_bounds__(256, 3) void attn_kernel(
    const ushort_t* __restrict__ Qh, const ushort_t* __restrict__ Kh,
    const ushort_t* __restrict__ VT, const float* __restrict__ params,
    ushort_t* __restrict__ Oh)
{
  constexpr int TS = 64 * 72;                  // one K or V tile (elems)
  __shared__ __align__(16) ushort_t KV[4 * TS]; // [p][K|V], 36.9 KB; Om/lwS overlay after loop
  __shared__ ushort_t Ps[4][16 * 40];          // per-wave P slab 16x(32+8pad), 5 KB
  __shared__ float loS[4], hiS[4];

  const int tid = threadIdx.x;
  const int lane = tid & 63, w = tid >> 6;
  const int wr = w >> 1, wc = w & 1;
  const int quad = lane >> 4, l16 = lane & 15;
  const int bh = blockIdx.x;
  const int mrow = blockIdx.y * 32;
  ushort_t* Pw = Ps[w];

  s16x8 aq0 = *(const s16x8*)(Qh + (bh * 1024 + mrow + wr * 16 + l16) * 64 + quad * 8);
  s16x8 aq1 = *(const s16x8*)(Qh + (bh * 1024 + mrow + wr * 16 + l16) * 64 + 32 + quad * 8);

  float bl[4], br[4], al[4], wl[4], wr2[4], da[4];
  float lo = 1.0e9f, hi = -1.0e9f;
#pragma unroll
  for (int rr = 0; rr < 4; rr++) {
    int row = mrow + wr * 16 + quad * 4 + rr;
    const float* pp = params + (bh * 1024 + row) * 6;
    bl[rr] = pp[0]; br[rr] = pp[1]; al[rr] = pp[2];
    wl[rr] = pp[3]; wr2[rr] = pp[4]; da[rr] = pp[5];
    bool empty = (br[rr] < 0.f) || (bl[rr] > 1023.f);
    float lo_r = empty ? 0.f    : fmaxf(bl[rr], 0.f);
    float hi_r = empty ? 1023.f : fminf(br[rr], 1023.f);
    lo = fminf(lo, lo_r); hi = fmaxf(hi, hi_r);
  }
  lo = fminf(lo, __shfl_xor(lo, 16));
  lo = fminf(lo, __shfl_xor(lo, 32));
  hi = fmaxf(hi, __shfl_xor(hi, 16));
  hi = fmaxf(hi, __shfl_xor(hi, 32));
  if (lane == 0) { loS[w] = lo; hiS[w] = hi; }
  __syncthreads();
  lo = fminf(fminf(loS[0], loS[1]), fminf(loS[2], loS[3]));
  hi = fmaxf(fmaxf(hiS[0], hiS[1]), fmaxf(hiS[2], hiS[3]));
  const int tlo = ((int)lo) >> 6, thi = ((int)hi) >> 6;   // block-uniform

  float lr[4] = {0.f, 0.f, 0.f, 0.f};
  f32x4 Oacc[4];
#pragma unroll
  for (int nt = 0; nt < 4; nt++) Oacc[nt] = f32x4{0.f, 0.f, 0.f, 0.f};

  // staging: thread -> row tid>>2 (0..63), 16-elem segment (tid&3)*16
  const int srow = tid >> 2, sseg = (tid & 3) * 16;
  const ushort_t* kgb = Kh + (bh * 1024 + srow) * 64 + sseg;   // + r0*64
  const ushort_t* vgb = VT + (bh * 64 + srow) * 1024 + sseg;   // + r0

  // prologue: load + write tile tlo into buffer 0
  s16x8 kr0, kr1, vr0, vr1;
  {
    const int r0 = tlo * 64;
    kr0 = *(const s16x8*)(kgb + r0 * 64);
    kr1 = *(const s16x8*)(kgb + r0 * 64 + 8);
    vr0 = *(const s16x8*)(vgb + r0);
    vr1 = *(const s16x8*)(vgb + r0 + 8);
  }
  {
    ushort_t* Kt = KV;
    ushort_t* Vt = KV + TS;
    *(s16x8*)(Kt + srow * 72 + sseg)     = kr0;
    *(s16x8*)(Kt + srow * 72 + sseg + 8) = kr1;
    *(s16x8*)(Vt + srow * 72 + sseg)     = vr0;
    *(s16x8*)(Vt + srow * 72 + sseg + 8) = vr1;
  }
  __syncthreads();

  for (int tt = tlo; tt <= thi; tt++) {
    const int p = (tt - tlo) & 1;
    ushort_t* Ktp = KV + p * 2 * TS;
    ushort_t* Vtp = KV + p * 2 * TS + TS;
    const int r0 = tt * 64;
    const bool more = (tt + 1 <= thi);

    if (more) {                          // next tile's global loads in flight
      const int r1 = (tt + 1) * 64;
      kr0 = *(const s16x8*)(kgb + r1 * 64);
      kr1 = *(const s16x8*)(kgb + r1 * 64 + 8);
      vr0 = *(const s16x8*)(vgb + r1);
      vr1 = *(const s16x8*)(vgb + r1 + 8);
    }

    // QK^T: this wave's 16 rows x 32 cols (2 col-groups)
    f32x4 S[2];
#pragma unroll
    for (int ng = 0; ng < 2; ng++) {
      const ushort_t* kp = Ktp + (wc * 32 + ng * 16 + l16) * 72 + quad * 8;
      s16x8 bk0 = *(const s16x8*)(kp);
      s16x8 bk1 = *(const s16x8*)(kp + 32);
      f32x4 z = {0.f, 0.f, 0.f, 0.f};
      z = __builtin_amdgcn_mfma_f32_16x16x32_bf16(aq0, bk0, z, 0, 0, 0);
      z = __builtin_amdgcn_mfma_f32_16x16x32_bf16(aq1, bk1, z, 0, 0, 0);
      S[ng] = z;
    }

    // softmax over the wave's 32-col window
    const int cbase = r0 + wc * 32;
    const float c0f = (float)cbase, c1f = c0f + 31.f;
    bool fastb = true;
#pragma unroll
    for (int rr = 0; rr < 4; rr++) {
      bool f = (bl[rr] < c0f) && (br[rr] > c1f) &&
               ((al[rr] + 1.f < c0f) || (al[rr] > c1f));
      fastb = fastb && f;
    }
    float p8[2][4];
    if (__all((int)fastb)) {
#pragma unroll
      for (int ng = 0; ng < 2; ng++)
#pragma unroll
        for (int rr = 0; rr < 4; rr++) {
          float pv = __expf(S[ng][rr]);
          lr[rr] += pv;
          p8[ng][rr] = pv;
        }
    } else {
#pragma unroll
      for (int ng = 0; ng < 2; ng++) {
        const float cf = (float)(cbase + ng * 16 + l16);
#pragma unroll
        for (int rr = 0; rr < 4; rr++) {
          float s = S[ng][rr];           // includes 0.125 via Qh pre-scale
          float wgt = 1.f;
          wgt += (cf == bl[rr]) ? wl[rr] : 0.f;
          wgt += (cf == br[rr]) ? wr2[rr] : 0.f;
          wgt += (cf == al[rr] + 1.f) ? da[rr] : 0.f;
          wgt += (cf == al[rr]) ? (1.f - da[rr]) : 0.f;
          s *= wgt;
          s = (cf < bl[rr] || cf > br[rr]) ? -30.f : s;
          float pv = __expf(s);
          lr[rr] += pv;
          p8[ng][rr] = pv;
        }
      }
    }

    // P (C-layout) -> wave-private slab: exact 16x32 A-operand
#pragma unroll
    for (int ng = 0; ng < 2; ng++)
#pragma unroll
      for (int rr = 0; rr < 4; rr++)
        Pw[(quad * 4 + rr) * 40 + ng * 16 + l16] = f2b_hw(p8[ng][rr]);

    s16x8 pa = *(const s16x8*)(Pw + l16 * 40 + quad * 8);

    // PV: B[k=local t in wave's 32-col window][n=d] from Vt row d
#pragma unroll
    for (int nt = 0; nt < 4; nt++) {
      s16x8 bv = *(const s16x8*)(Vtp + (nt * 16 + l16) * 72 + wc * 32 + quad * 8);
      Oacc[nt] = __builtin_amdgcn_mfma_f32_16x16x32_bf16(pa, bv, Oacc[nt], 0, 0, 0);
    }

    if (more) {                          // write next tile, ONE barrier per tile
      ushort_t* Ktn = KV + (p ^ 1) * 2 * TS;
      ushort_t* Vtn = KV + (p ^ 1) * 2 * TS + TS;
      *(s16x8*)(Ktn + srow * 72 + sseg)     = kr0;
      *(s16x8*)(Ktn + srow * 72 + sseg + 8) = kr1;
      *(s16x8*)(Vtn + srow * 72 + sseg)     = vr0;
      *(s16x8*)(Vtn + srow * 72 + sseg + 8) = vr1;
      __syncthreads();
    }
  }

  // per-wave row sums over its 32 cols
#pragma unroll
  for (int mask = 1; mask < 16; mask <<= 1)
#pragma unroll
    for (int rr = 0; rr < 4; rr++) lr[rr] += __shfl_xor(lr[rr], mask);

  // overlay merge scratch onto dead staging buffers (barrier-separated)
  __syncthreads();
  float* Om  = (float*)KV;               // [wc*32 + row][65]
  float* lwf = Om + 2 * 32 * 65;         // [wc*32 + row]
  const int rloc = wr * 16 + quad * 4;
#pragma unroll
  for (int nt = 0; nt < 4; nt++)
#pragma unroll
    for (int rr = 0; rr < 4; rr++)
      Om[(wc * 32 + rloc + rr) * 65 + nt * 16 + l16] = Oacc[nt][rr];
  if (l16 == 0) {
#pragma unroll
    for (int rr = 0; rr < 4; rr++) lwf[wc * 32 + rloc + rr] = lr[rr];
  }
  __syncthreads();

  // merge 2 col-half partials (fixed m=0 -> plain sums): 32x64 elems / 256 thr
  const int bb = bh >> 3, h = bh & 7;
  for (int e = tid; e < 2048; e += 256) {
    int r = e >> 6, col = e & 63;
    float lg = lwf[r] + lwf[32 + r];
    float o  = Om[r * 65 + col] + Om[(32 + r) * 65 + col];
    int t = mrow + r;
    Oh[((bb << 10) + t) * 512 + h * 64 + col] = f2b_hw(o / lg);
  }
}

// ------- out GEMM: 64x64 tiles, grid (8,32)=256 blocks -------
__global__ __launch_bounds__(256) void out_gemm_kernel(
    const ushort_t* __restrict__ Oh, const ushort_t* __restrict__ WT,
    const float* __restrict__ bout, float* __restrict__ outp)
{
  __shared__ ushort_t As[64 * 32];
  __shared__ ushort_t Bs[64 * 32];
  const int tid = threadIdx.x;
  const int lane = tid & 63, w = tid >> 6;
  const int wr = w >> 1, wc = w & 1;          // wave tile 32x32
  const int quad = lane >> 4, l16 = lane & 15;
  const int m0 = blockIdx.y * 64, n0 = blockIdx.x * 64;

  f32x4 acc[2][2];
#pragma unroll
  for (int i = 0; i < 2; i++)
#pragma unroll
    for (int j = 0; j < 2; j++) acc[i][j] = f32x4{0.f, 0.f, 0.f, 0.f};

  const int idx = tid * 8;
  const int ra = idx >> 5, ca = idx & 31;

  for (int k0 = 0; k0 < 512; k0 += 32) {
    s16x8 va = *(const s16x8*)(Oh + (m0 + ra) * 512 + k0 + ca);
    s16x8 vb = *(const s16x8*)(WT + (n0 + ra) * 512 + k0 + ca);
    __syncthreads();
    *(s16x8*)(As + idx) = va;
    *(s16x8*)(Bs + idx) = vb;
    __syncthreads();

    s16x8 af[2], bfr[2];
#pragma unroll
    for (int mt = 0; mt < 2; mt++)
      af[mt] = *(const s16x8*)(As + (wr * 32 + mt * 16 + l16) * 32 + quad * 8);
#pragma unroll
    for (int nt = 0; nt < 2; nt++)
      bfr[nt] = *(const s16x8*)(Bs + (wc * 32 + nt * 16 + l16) * 32 + quad * 8);
#pragma unroll
    for (int mt = 0; mt < 2; mt++)
#pragma unroll
      for (int nt = 0; nt < 2; nt++)
        acc[mt][nt] = __builtin_amdgcn_mfma_f32_16x16x32_bf16(af[mt], bfr[nt], acc[mt][nt], 0, 0, 0);
  }

#pragma unroll
  for (int nt = 0; nt < 2; nt++) {
    int c = n0 + wc * 32 + nt * 16 + l16;
    float bias = bout[c];
#pragma unroll
    for (int mt = 0; mt < 2; mt++) {
#pragma unroll
      for (int rr = 0; rr < 4; rr++) {
        int m = m0 + wr * 32 + mt * 16 + quad * 4 + rr;
        outp[m * 512 + c] = acc[mt][nt][rr] + bias;
      }
    }
  }
}

extern "C" void kernel_launch(void* const* d_in, const int* in_sizes, int n_in,
                              void* d_out, int out_size, void* d_ws, size_t ws_size,
                              hipStream_t stream)
{
  const float* x    = (const float*)d_in[0];
  const float* Wqkv = (const float*)d_in[1];
  const float* bqkv = (const float*)d_in[2];
  const float* Wod  = (const float*)d_in[3];
  const float* bod  = (const float*)d_in[4];
  const float* Wout = (const float*)d_in[5];
  const float* bout = (const float*)d_in[6];
  const int* lenp   = (const int*)d_in[7];

  char* ws = (char*)d_ws;
  ushort_t* WqkvT  = (ushort_t*)(ws);                  // 1536x512 bf16
  ushort_t* WoT    = (ushort_t*)(ws + 1572864);        // 512x512 bf16
  ushort_t* xb     = (ushort_t*)(ws + 2097152);        // 2048x512 bf16
  ushort_t* Qh     = (ushort_t*)(ws + 4194304);        // 16x1024x64 bf16 (pre-scaled 0.125)
  ushort_t* Kh     = (ushort_t*)(ws + 6291456);        // 16x1024x64 bf16
  ushort_t* VT     = (ushort_t*)(ws + 8388608);        // 16x64x1024 bf16
  ushort_t* Oh     = (ushort_t*)(ws + 10485760);       // 2048x512 bf16
  float*    Wcomb  = (float*)(ws + 12582912);          // 512x16 f32
  float*    bcomb  = (float*)(ws + 12615680);          // 16 f32
  float*    params = (float*)(ws + 12615744);          // 16x1024x6 f32

  prep_kernel<<<385, 256, 0, stream>>>(Wqkv, bqkv, Wod, bod, Wout, WqkvT, WoT, Wcomb, bcomb);
  od_kernel<<<512, 256, 0, stream>>>(x, Wcomb, bcomb, lenp, params, xb);
  qkv_gemm_kernel<<<dim3(12, 32), 256, 0, stream>>>(xb, WqkvT, bqkv, Qh, Kh, VT);
  attn_kernel<<<dim3(16, 32), 256, 0, stream>>>(Qh, Kh, VT, params, Oh);
  out_gemm_kernel<<<dim3(8, 32), 256, 0, stream>>>(Oh, WoT, bout, (float*)d_out);
}

// Round 15
// 126.289 us; speedup vs baseline: 1.1054x; 1.0242x over previous
//
#include <hip/hip_runtime.h>

typedef unsigned short ushort_t;
typedef short s16x8 __attribute__((ext_vector_type(8)));   // bf16 frag vector (K=32 ops)
typedef short s16x4 __attribute__((ext_vector_type(4)));   // bf16 frag vector (K=16 ops)
typedef float f32x4 __attribute__((ext_vector_type(4)));

// Device pass has __builtin_amdgcn_mfma_f32_16x16x16bf16_1k (round-13 log:
// only HOST pass errored). __has_builtin can't see aux-target builtins in the
// host pass, so gate on __HIP_DEVICE_COMPILE__. The host-pass stub must be
// __device__ __host__ because the host pass semantically checks __global__
// bodies (round-14 error) — it never codegens for device.
#if defined(__HIP_DEVICE_COMPILE__)
#define MFMA16(a, b, c) __builtin_amdgcn_mfma_f32_16x16x16bf16_1k(a, b, c, 0, 0, 0)
#else
__device__ __host__ static inline f32x4 MFMA16(s16x4, s16x4, f32x4 c) { return c; }
#endif

#define DEVINL __device__ __forceinline__

DEVINL ushort_t f2b(float f) {           // fp32 -> bf16 RNE
  union { float f; unsigned int u; } v; v.f = f;
  unsigned int r = (v.u + 0x7fffu + ((v.u >> 16) & 1u)) >> 16;
  return (ushort_t)r;
}

DEVINL ushort_t f2b_hw(float f) {        // fp32 -> bf16 via HW v_cvt (RNE)
  union { __bf16 h; ushort_t u; } cv;
  cv.h = (__bf16)f;
  return cv.u;
}

// ---------- prep: fused {Wqkv transpose, Wout transpose, fold} ----------
__global__ __launch_bounds__(256) void prep_kernel(
    const float* __restrict__ Wqkv, const float* __restrict__ bq,
    const float* __restrict__ Wod, const float* __restrict__ bod,
    const float* __restrict__ Wout,
    ushort_t* __restrict__ WqkvT, ushort_t* __restrict__ WoT,
    float* __restrict__ Wcomb, float* __restrict__ bcomb)
{
  __shared__ ushort_t tile[64 * 72];
  const int b = blockIdx.x;
  const int tid = threadIdx.x;

  if (b < 256) {
    const float* in;
    ushort_t* out;
    int N, bx, by;
    if (b < 192) { in = Wqkv; out = WqkvT; N = 1536; bx = b % 24; by = b / 24; }
    else         { in = Wout; out = WoT;   N = 512;  bx = (b - 192) % 8; by = (b - 192) / 8; }
    const int K = 512;
    const int n0 = bx * 64, k0 = by * 64;
    const int cr = tid >> 4;
    const int cc = (tid & 15) * 4;
#pragma unroll
    for (int p = 0; p < 4; p++) {
      int k = k0 + p * 16 + cr;
      float4 v = *(const float4*)(in + k * N + n0 + cc);
      ushort4 o; o.x = f2b(v.x); o.y = f2b(v.y); o.z = f2b(v.z); o.w = f2b(v.w);
      *(ushort4*)(tile + (p * 16 + cr) * 72 + cc) = o;
    }
    __syncthreads();
#pragma unroll
    for (int p = 0; p < 4; p++) {
      int n = n0 + p * 16 + cr;
      ushort4 v;
      v.x = tile[(cc + 0) * 72 + p * 16 + cr];
      v.y = tile[(cc + 1) * 72 + p * 16 + cr];
      v.z = tile[(cc + 2) * 72 + p * 16 + cr];
      v.w = tile[(cc + 3) * 72 + p * 16 + cr];
      *(ushort4*)(out + n * K + k0 + cc) = v;
    }
    return;
  }

  // fold: one wave per c-row
  const int w = tid >> 6, lane = tid & 63;
  const int c = (b - 256) * 4 + w;
  if (c > 512) return;
  float a[8];
  const float* src = (c < 512) ? (Wqkv + c * 1536 + lane * 8) : (bq + lane * 8);
  float4 a0 = *(const float4*)(src);
  float4 a1 = *(const float4*)(src + 4);
  a[0]=a0.x; a[1]=a0.y; a[2]=a0.z; a[3]=a0.w;
  a[4]=a1.x; a[5]=a1.y; a[6]=a1.z; a[7]=a1.w;

  float s[16];
#pragma unroll
  for (int j = 0; j < 16; j++) s[j] = 0.f;
#pragma unroll
  for (int i = 0; i < 8; i++) {
    const float* wp = Wod + (lane * 8 + i) * 16;
#pragma unroll
    for (int j = 0; j < 16; j++) s[j] += a[i] * wp[j];
  }
#pragma unroll
  for (int mask = 1; mask < 64; mask <<= 1)
#pragma unroll
    for (int j = 0; j < 16; j++) s[j] += __shfl_xor(s[j], mask);

  if (lane < 16) {
    if (c < 512) Wcomb[c * 16 + lane] = s[lane];
    else         bcomb[lane] = s[lane] + bod[lane];
  }
}

// ------- merged qkv GEMM + od: blocks [0,384) gemm, [384,896) od -------
__global__ __launch_bounds__(256) void qkv_od_kernel(
    const float* __restrict__ x, const ushort_t* __restrict__ WT,
    const float* __restrict__ bqkv,
    const float* __restrict__ Wcomb, const float* __restrict__ bcomb,
    const int* __restrict__ lenp,
    ushort_t* __restrict__ Qh, ushort_t* __restrict__ Kh, ushort_t* __restrict__ VT,
    float* __restrict__ params)
{
  const int blk = blockIdx.x;
  const int tid = threadIdx.x;

  if (blk >= 384) {
    // ---- od path ----
    const int w = tid >> 6, lane = tid & 63;
    const int m = (blk - 384) * 4 + w;   // 0..2047
    int li = lenp[0];
    float len = (li > 0 && li < 1048576) ? (float)li : 1024.0f;

    const float* qp = x + m * 512 + lane * 8;
    float q[8];
    float4 qa = *(const float4*)(qp);
    float4 qb = *(const float4*)(qp + 4);
    q[0]=qa.x; q[1]=qa.y; q[2]=qa.z; q[3]=qa.w;
    q[4]=qb.x; q[5]=qb.y; q[6]=qb.z; q[7]=qb.w;

    float s[16];
#pragma unroll
    for (int j = 0; j < 16; j++) s[j] = 0.f;
#pragma unroll
    for (int i = 0; i < 8; i++) {
      const float* wp = Wcomb + (lane * 8 + i) * 16;
#pragma unroll
      for (int j = 0; j < 16; j++) s[j] += q[i] * wp[j];
    }
#pragma unroll
    for (int mask = 1; mask < 64; mask <<= 1)
#pragma unroll
      for (int j = 0; j < 16; j++) s[j] += __shfl_xor(s[j], mask);

    if (lane < 8) {
      int h = lane;
      int bb = m >> 10, t = m & 1023;
      float odo = s[h] + bcomb[h];
      float odd = s[8 + h] + bcomb[8 + h];
      float offset = tanhf(odo) * len;
      float dur = len / (1.f + expf(-odd));
      float anchor = (float)t + offset;
      float start = anchor - dur, end = anchor + dur;
      float bl = floorf(start), br = ceilf(end);
      float al = floorf(anchor);
      float da = anchor - al;
      float* pp = params + ((bb * 8 + h) * 1024 + t) * 6;
      pp[0] = bl; pp[1] = br; pp[2] = al;
      pp[3] = bl - start; pp[4] = end - br; pp[5] = da;
    }
    return;
  }

  // ---- qkv gemm path ----
  __shared__ ushort_t As[64 * 32];
  __shared__ ushort_t Bs[128 * 32];
  const int lane = tid & 63, w = tid >> 6;
  const int wr = w >> 1, wc = w & 1;          // wave tile 32x64
  const int quad = lane >> 4, l16 = lane & 15;
  const int bx = blk % 12, by = blk / 12;
  const int m0 = by * 64, n0 = bx * 128;

  f32x4 acc[2][4];
#pragma unroll
  for (int i = 0; i < 2; i++)
#pragma unroll
    for (int j = 0; j < 4; j++) acc[i][j] = f32x4{0.f, 0.f, 0.f, 0.f};

  const int idx = tid * 8;
  const int ra = idx >> 5, ca = idx & 31;
  const int rb1 = (idx + 2048) >> 5, cb1 = (idx + 2048) & 31;

  for (int k0 = 0; k0 < 512; k0 += 32) {
    const float* xa = x + (m0 + ra) * 512 + k0 + ca;
    float4 x0 = *(const float4*)(xa);
    float4 x1 = *(const float4*)(xa + 4);
    s16x8 vb0 = *(const s16x8*)(WT + (n0 + ra) * 512 + k0 + ca);
    s16x8 vb1 = *(const s16x8*)(WT + (n0 + rb1) * 512 + k0 + cb1);
    s16x8 va;
    va[0] = (short)f2b_hw(x0.x); va[1] = (short)f2b_hw(x0.y);
    va[2] = (short)f2b_hw(x0.z); va[3] = (short)f2b_hw(x0.w);
    va[4] = (short)f2b_hw(x1.x); va[5] = (short)f2b_hw(x1.y);
    va[6] = (short)f2b_hw(x1.z); va[7] = (short)f2b_hw(x1.w);
    __syncthreads();
    *(s16x8*)(As + idx) = va;
    *(s16x8*)(Bs + idx) = vb0;
    *(s16x8*)(Bs + idx + 2048) = vb1;
    __syncthreads();

    s16x8 af[2], bfr[4];
#pragma unroll
    for (int mt = 0; mt < 2; mt++)
      af[mt] = *(const s16x8*)(As + (wr * 32 + mt * 16 + l16) * 32 + quad * 8);
#pragma unroll
    for (int nt = 0; nt < 4; nt++)
      bfr[nt] = *(const s16x8*)(Bs + (wc * 64 + nt * 16 + l16) * 32 + quad * 8);
#pragma unroll
    for (int mt = 0; mt < 2; mt++)
#pragma unroll
      for (int nt = 0; nt < 4; nt++)
        acc[mt][nt] = __builtin_amdgcn_mfma_f32_16x16x32_bf16(af[mt], bfr[nt], acc[mt][nt], 0, 0, 0);
  }

#pragma unroll
  for (int nt = 0; nt < 4; nt++) {
    int c = n0 + wc * 64 + nt * 16 + l16;
    float bias = bqkv[c];
    int which = c >> 9;
    int e = c & 511;
    int h = e >> 6, d = e & 63;
#pragma unroll
    for (int mt = 0; mt < 2; mt++) {
      int mbase = m0 + wr * 32 + mt * 16 + quad * 4;
      int bb = mbase >> 10, t = mbase & 1023;
      int bh = bb * 8 + h;
      if (which == 2) {
        ushort4 pk;
        pk.x = f2b(acc[mt][nt][0] + bias);
        pk.y = f2b(acc[mt][nt][1] + bias);
        pk.z = f2b(acc[mt][nt][2] + bias);
        pk.w = f2b(acc[mt][nt][3] + bias);
        *(ushort4*)(VT + (bh * 64 + d) * 1024 + t) = pk;
      } else {
        ushort_t* dst = (which == 0) ? Qh : Kh;
        float sc = (which == 0) ? 0.125f : 1.0f;
#pragma unroll
        for (int rr = 0; rr < 4; rr++)
          dst[(bh * 1024 + t + rr) * 64 + d] = f2b((acc[mt][nt][rr] + bias) * sc);
      }
    }
  }
}

// ------- attention v3: chained K=16 MFMA, register-resident P -------
// S^T = K.Q^T  (C/D layout: col=q=l16, row=kc=quad*4+reg), exp in place,
// P^T is then directly a B-operand (k=quad*4+j, n=l16) for O^T = V^T.P^T.
// Block = (bh, 16 Q-rows), 1024 blocks; wave wc owns 16 K-cols of each
// 64-col tile; ping-pong K/V staging, ONE barrier per tile; LDS 36.9 KB
// -> 4 blocks/CU.
__global__ __launch_bounds__(256, 4) void attn_kernel(
    const ushort_t* __restrict__ Qh, const ushort_t* __restrict__ Kh,
    const ushort_t* __restrict__ VT, const float* __restrict__ params,
    ushort_t* __restrict__ Oh)
{
  constexpr int TS = 64 * 72;                   // one K or V tile (elems)
  __shared__ __align__(16) ushort_t KV[4 * TS]; // [p][K|V], 36.9 KB; merge overlay after loop

  const int tid = threadIdx.x;
  const int lane = tid & 63, wc = tid >> 6;     // wave = col-quarter
  const int quad = lane >> 4, l16 = lane & 15;
  const int bh = blockIdx.x;
  const int mrow = blockIdx.y * 16;

  // params per lane: row q = l16 (quads redundant by construction)
  const float* ppl = params + (bh * 1024 + mrow + l16) * 6;
  float bl = ppl[0], br = ppl[1], al = ppl[2];
  float wl = ppl[3], wr2 = ppl[4], da = ppl[5];
  bool empty = (br < 0.f) || (bl > 1023.f);
  float lo = empty ? 0.f    : fmaxf(bl, 0.f);
  float hi = empty ? 1023.f : fminf(br, 1023.f);
#pragma unroll
  for (int mask = 1; mask < 16; mask <<= 1) {
    lo = fminf(lo, __shfl_xor(lo, mask));
    hi = fmaxf(hi, __shfl_xor(hi, mask));
  }
  const int tlo = ((int)lo) >> 6, thi = ((int)hi) >> 6;   // block-uniform

  // Q fragments (B-operand): bq[i][k=quad*4+j] = Q[q=l16][i*16+quad*4+j]
  const ushort_t* qrow = Qh + (bh * 1024 + mrow + l16) * 64;
  s16x4 bq[4];
#pragma unroll
  for (int i = 0; i < 4; i++)
    bq[i] = *(const s16x4*)(qrow + i * 16 + quad * 4);

  float lr = 0.f;
  f32x4 Oacc[4];
#pragma unroll
  for (int g = 0; g < 4; g++) Oacc[g] = f32x4{0.f, 0.f, 0.f, 0.f};

  // staging: thread -> row tid>>2 (0..63), 16-elem segment (tid&3)*16
  const int srow = tid >> 2, sseg = (tid & 3) * 16;
  const ushort_t* kgb = Kh + (bh * 1024 + srow) * 64 + sseg;   // + r0*64
  const ushort_t* vgb = VT + (bh * 64 + srow) * 1024 + sseg;   // + r0

  s16x8 kr0, kr1, vr0, vr1;
  {
    const int r0 = tlo * 64;
    kr0 = *(const s16x8*)(kgb + r0 * 64);
    kr1 = *(const s16x8*)(kgb + r0 * 64 + 8);
    vr0 = *(const s16x8*)(vgb + r0);
    vr1 = *(const s16x8*)(vgb + r0 + 8);
  }
  {
    ushort_t* Kt = KV;
    ushort_t* Vt = KV + TS;
    *(s16x8*)(Kt + srow * 72 + sseg)     = kr0;
    *(s16x8*)(Kt + srow * 72 + sseg + 8) = kr1;
    *(s16x8*)(Vt + srow * 72 + sseg)     = vr0;
    *(s16x8*)(Vt + srow * 72 + sseg + 8) = vr1;
  }
  __syncthreads();

  for (int tt = tlo; tt <= thi; tt++) {
    const int p = (tt - tlo) & 1;
    ushort_t* Ktp = KV + p * 2 * TS;
    ushort_t* Vtp = KV + p * 2 * TS + TS;
    const int r0 = tt * 64;
    const bool more = (tt + 1 <= thi);

    if (more) {                          // next tile's global loads in flight
      const int r1 = (tt + 1) * 64;
      kr0 = *(const s16x8*)(kgb + r1 * 64);
      kr1 = *(const s16x8*)(kgb + r1 * 64 + 8);
      vr0 = *(const s16x8*)(vgb + r1);
      vr1 = *(const s16x8*)(vgb + r1 + 8);
    }

    // S^T = K.Q^T over this wave's 16 K-cols (kc = wc*16 + ...)
    const ushort_t* krow = Ktp + (wc * 16 + l16) * 72;
    f32x4 z = {0.f, 0.f, 0.f, 0.f};
#pragma unroll
    for (int i = 0; i < 4; i++) {
      s16x4 ak = *(const s16x4*)(krow + i * 16 + quad * 4);
      z = MFMA16(ak, bq[i], z);          // D[kc][q]
    }

    // softmax: lane handles q=l16, kc = cbase + quad*4 + rr
    const int cbase = r0 + wc * 16;
    const float c0f = (float)cbase, c1f = c0f + 15.f;
    bool f = (bl < c0f) && (br > c1f) && ((al + 1.f < c0f) || (al > c1f));
    s16x4 pt;
    if (__all((int)f)) {
#pragma unroll
      for (int rr = 0; rr < 4; rr++) {
        float pv = __expf(z[rr]);
        lr += pv;
        pt[rr] = (short)f2b_hw(pv);
      }
    } else {
#pragma unroll
      for (int rr = 0; rr < 4; rr++) {
        float cf = (float)(cbase + quad * 4 + rr);
        float s = z[rr];                 // includes 0.125 via Qh pre-scale
        float wgt = 1.f;
        wgt += (cf == bl) ? wl : 0.f;
        wgt += (cf == br) ? wr2 : 0.f;
        wgt += (cf == al + 1.f) ? da : 0.f;
        wgt += (cf == al) ? (1.f - da) : 0.f;
        s *= wgt;
        s = (cf < bl || cf > br) ? -30.f : s;
        float pv = __expf(s);
        lr += pv;
        pt[rr] = (short)f2b_hw(pv);
      }
    }

    // O^T = V^T.P^T : A = V^T frag (m=d local, k=kc local), B = pt (register P!)
#pragma unroll
    for (int g = 0; g < 4; g++) {
      s16x4 av = *(const s16x4*)(Vtp + (g * 16 + l16) * 72 + wc * 16 + quad * 4);
      Oacc[g] = MFMA16(av, pt, Oacc[g]); // D[d][q]
    }

    if (more) {                          // write next tile, ONE barrier per tile
      ushort_t* Ktn = KV + (p ^ 1) * 2 * TS;
      ushort_t* Vtn = KV + (p ^ 1) * 2 * TS + TS;
      *(s16x8*)(Ktn + srow * 72 + sseg)     = kr0;
      *(s16x8*)(Ktn + srow * 72 + sseg + 8) = kr1;
      *(s16x8*)(Vtn + srow * 72 + sseg)     = vr0;
      *(s16x8*)(Vtn + srow * 72 + sseg + 8) = vr1;
      __syncthreads();
    }
  }

  // row-sum: each quad covered distinct kc -> reduce across quads
  lr += __shfl_xor(lr, 16);
  lr += __shfl_xor(lr, 32);

  // merge scratch overlays dead staging LDS (barrier-separated)
  __syncthreads();
  float* Om  = (float*)KV;               // [wc*16 + q][65]
  float* lwf = Om + 64 * 65;             // [wc*16 + q]
#pragma unroll
  for (int g = 0; g < 4; g++)
#pragma unroll
    for (int rr = 0; rr < 4; rr++)
      Om[(wc * 16 + l16) * 65 + g * 16 + quad * 4 + rr] = Oacc[g][rr];
  if (quad == 0) lwf[wc * 16 + l16] = lr;
  __syncthreads();

  // merge 4 col-quarter partials (fixed m=0 -> plain sums): 16x64 / 256 thr
  const int bb = bh >> 3, h = bh & 7;
  {
    int e = tid;                          // 1024 elems, 256 threads, 4 each
#pragma unroll
    for (int it = 0; it < 4; it++, e += 256) {
      int r = e >> 6, col = e & 63;
      float lg = lwf[r] + lwf[16 + r] + lwf[32 + r] + lwf[48 + r];
      float o  = Om[r * 65 + col] + Om[(16 + r) * 65 + col]
               + Om[(32 + r) * 65 + col] + Om[(48 + r) * 65 + col];
      int t = mrow + r;
      Oh[((bb << 10) + t) * 512 + h * 64 + col] = f2b_hw(o / lg);
    }
  }
}

// ------- out GEMM: 64x64 tiles, grid (8,32)=256 blocks -------
__global__ __launch_bounds__(256) void out_gemm_kernel(
    const ushort_t* __restrict__ Oh, const ushort_t* __restrict__ WT,
    const float* __restrict__ bout, float* __restrict__ outp)
{
  __shared__ ushort_t As[64 * 32];
  __shared__ ushort_t Bs[64 * 32];
  const int tid = threadIdx.x;
  const int lane = tid & 63, w = tid >> 6;
  const int wr = w >> 1, wc = w & 1;          // wave tile 32x32
  const int quad = lane >> 4, l16 = lane & 15;
  const int m0 = blockIdx.y * 64, n0 = blockIdx.x * 64;

  f32x4 acc[2][2];
#pragma unroll
  for (int i = 0; i < 2; i++)
#pragma unroll
    for (int j = 0; j < 2; j++) acc[i][j] = f32x4{0.f, 0.f, 0.f, 0.f};

  const int idx = tid * 8;
  const int ra = idx >> 5, ca = idx & 31;

  for (int k0 = 0; k0 < 512; k0 += 32) {
    s16x8 va = *(const s16x8*)(Oh + (m0 + ra) * 512 + k0 + ca);
    s16x8 vb = *(const s16x8*)(WT + (n0 + ra) * 512 + k0 + ca);
    __syncthreads();
    *(s16x8*)(As + idx) = va;
    *(s16x8*)(Bs + idx) = vb;
    __syncthreads();

    s16x8 af[2], bfr[2];
#pragma unroll
    for (int mt = 0; mt < 2; mt++)
      af[mt] = *(const s16x8*)(As + (wr * 32 + mt * 16 + l16) * 32 + quad * 8);
#pragma unroll
    for (int nt = 0; nt < 2; nt++)
      bfr[nt] = *(const s16x8*)(Bs + (wc * 32 + nt * 16 + l16) * 32 + quad * 8);
#pragma unroll
    for (int mt = 0; mt < 2; mt++)
#pragma unroll
      for (int nt = 0; nt < 2; nt++)
        acc[mt][nt] = __builtin_amdgcn_mfma_f32_16x16x32_bf16(af[mt], bfr[nt], acc[mt][nt], 0, 0, 0);
  }

#pragma unroll
  for (int nt = 0; nt < 2; nt++) {
    int c = n0 + wc * 32 + nt * 16 + l16;
    float bias = bout[c];
#pragma unroll
    for (int mt = 0; mt < 2; mt++) {
#pragma unroll
      for (int rr = 0; rr < 4; rr++) {
        int m = m0 + wr * 32 + mt * 16 + quad * 4 + rr;
        outp[m * 512 + c] = acc[mt][nt][rr] + bias;
      }
    }
  }
}

extern "C" void kernel_launch(void* const* d_in, const int* in_sizes, int n_in,
                              void* d_out, int out_size, void* d_ws, size_t ws_size,
                              hipStream_t stream)
{
  const float* x    = (const float*)d_in[0];
  const float* Wqkv = (const float*)d_in[1];
  const float* bqkv = (const float*)d_in[2];
  const float* Wod  = (const float*)d_in[3];
  const float* bod  = (const float*)d_in[4];
  const float* Wout = (const float*)d_in[5];
  const float* bout = (const float*)d_in[6];
  const int* lenp   = (const int*)d_in[7];

  char* ws = (char*)d_ws;
  ushort_t* WqkvT  = (ushort_t*)(ws);                  // 1536x512 bf16
  ushort_t* WoT    = (ushort_t*)(ws + 1572864);        // 512x512 bf16
  ushort_t* Qh     = (ushort_t*)(ws + 4194304);        // 16x1024x64 bf16 (pre-scaled 0.125)
  ushort_t* Kh     = (ushort_t*)(ws + 6291456);        // 16x1024x64 bf16
  ushort_t* VT     = (ushort_t*)(ws + 8388608);        // 16x64x1024 bf16
  ushort_t* Oh     = (ushort_t*)(ws + 10485760);       // 2048x512 bf16
  float*    Wcomb  = (float*)(ws + 12582912);          // 512x16 f32
  float*    bcomb  = (float*)(ws + 12615680);          // 16 f32
  float*    params = (float*)(ws + 12615744);          // 16x1024x6 f32

  prep_kernel<<<385, 256, 0, stream>>>(Wqkv, bqkv, Wod, bod, Wout, WqkvT, WoT, Wcomb, bcomb);
  qkv_od_kernel<<<896, 256, 0, stream>>>(x, WqkvT, bqkv, Wcomb, bcomb, lenp,
                                         Qh, Kh, VT, params);
  attn_kernel<<<dim3(16, 64), 256, 0, stream>>>(Qh, Kh, VT, params, Oh);
  out_gemm_kernel<<<dim3(8, 32), 256, 0, stream>>>(Oh, WoT, bout, (float*)d_out);
}